// Round 1
// baseline (874.960 us; speedup 1.0000x reference)
//
#include <hip/hip_runtime.h>

#define HID 64

// ---------------- degree / norm ----------------
__global__ void deg_init_kernel(float* __restrict__ deg, int n) {
    int i = blockIdx.x * blockDim.x + threadIdx.x;
    if (i < n) deg[i] = 1.0f;   // self-loop contributes 1 to in-degree
}

__global__ void deg_accum_kernel(const int* __restrict__ dst, float* __restrict__ deg, int n_edges) {
    int i = blockIdx.x * blockDim.x + threadIdx.x;
    int stride = gridDim.x * blockDim.x;
    for (int e = i; e < n_edges; e += stride)
        atomicAdd(&deg[dst[e]], 1.0f);
}

__global__ void rsqrt_kernel(float* __restrict__ deg, int n) {
    int i = blockIdx.x * blockDim.x + threadIdx.x;
    if (i < n) deg[i] = rsqrtf(deg[i]);   // deg >= 1 always (self-loop)
}

// ---------------- GEMM: out[i][c] = dinv[i] * sum_k X[i][k]*W[c][k] ----------------
// One wave per node per iteration; lane = output channel; W row held in VGPRs.
template<int K>
__global__ void __launch_bounds__(256) gemm_scale_kernel(
    const float* __restrict__ X,     // [n][K]
    const float* __restrict__ W,     // [64][K]
    const float* __restrict__ dinv,  // [n]
    float* __restrict__ out,         // [n][64]
    int n) {
    const int lane = threadIdx.x & 63;
    int wid = blockIdx.x * (blockDim.x >> 6) + (threadIdx.x >> 6);
    const int nw = gridDim.x * (blockDim.x >> 6);

    float w[K];
#pragma unroll
    for (int k = 0; k < K; k += 4) {
        float4 v = *reinterpret_cast<const float4*>(W + lane * K + k);
        w[k] = v.x; w[k + 1] = v.y; w[k + 2] = v.z; w[k + 3] = v.w;
    }

    for (int node = wid; node < n; node += nw) {
        const float* xr = X + (size_t)node * K;
        float a0 = 0.f, a1 = 0.f, a2 = 0.f, a3 = 0.f;
#pragma unroll
        for (int k = 0; k < K; k += 4) {
            float4 v = *reinterpret_cast<const float4*>(xr + k);
            a0 += v.x * w[k];
            a1 += v.y * w[k + 1];
            a2 += v.z * w[k + 2];
            a3 += v.w * w[k + 3];
        }
        out[(size_t)node * HID + lane] = (a0 + a1 + a2 + a3) * dinv[node];
    }
}

// ---------------- float4 copy (self-loop init: agg = hs) ----------------
__global__ void copy_kernel(const float4* __restrict__ src, float4* __restrict__ dst, int n4) {
    int i = blockIdx.x * blockDim.x + threadIdx.x;
    int stride = gridDim.x * blockDim.x;
    for (; i < n4; i += stride) dst[i] = src[i];
}

// ---------------- edge scatter: agg[dst] += hs[src] ----------------
// One wave per edge; lane = channel. Coalesced 256B read + 64 contiguous atomics.
__global__ void scatter_kernel(const float* __restrict__ hs,
                               const int* __restrict__ src, const int* __restrict__ dst,
                               float* __restrict__ agg, int n_edges) {
    const int lane = threadIdx.x & 63;
    int wid = blockIdx.x * (blockDim.x >> 6) + (threadIdx.x >> 6);
    const int nw = gridDim.x * (blockDim.x >> 6);
    for (int e = wid; e < n_edges; e += nw) {
        int s = src[e];
        int d = dst[e];
        float v = hs[(size_t)s * HID + lane];
        atomicAdd(&agg[(size_t)d * HID + lane], v);
    }
}

// ---------------- h = relu(dinv[i]*agg + b[c]) ----------------
__global__ void bias_relu_kernel(const float* __restrict__ agg, const float* __restrict__ dinv,
                                 const float* __restrict__ b, float* __restrict__ out, int total) {
    int i = blockIdx.x * blockDim.x + threadIdx.x;
    int stride = gridDim.x * blockDim.x;
    for (; i < total; i += stride) {
        int node = i >> 6;
        int c = i & 63;
        float v = dinv[node] * agg[i] + b[c];
        out[i] = v > 0.f ? v : 0.f;
    }
}

// ---------------- scores[p] = sum_c h[u][c]*h[m][c]*fc_w[c] + fc_b ----------------
__global__ void final_kernel(const float* __restrict__ h,
                             const int* __restrict__ users, const int* __restrict__ movies,
                             const float* __restrict__ fc_w, const float* __restrict__ fc_b,
                             float* __restrict__ out, int batch) {
    const int lane = threadIdx.x & 63;
    int wid = blockIdx.x * (blockDim.x >> 6) + (threadIdx.x >> 6);
    const int nw = gridDim.x * (blockDim.x >> 6);
    for (int p = wid; p < batch; p += nw) {
        int u = users[p];
        int m = movies[p];
        float v = h[(size_t)u * HID + lane] * h[(size_t)m * HID + lane] * fc_w[lane];
#pragma unroll
        for (int off = 32; off > 0; off >>= 1)
            v += __shfl_down(v, off, 64);
        if (lane == 0) out[p] = v + fc_b[0];
    }
}

extern "C" void kernel_launch(void* const* d_in, const int* in_sizes, int n_in,
                              void* d_out, int out_size, void* d_ws, size_t ws_size,
                              hipStream_t stream) {
    const float* x     = (const float*)d_in[0];
    const int*   edge  = (const int*)d_in[1];   // [2][E]
    const int*   users = (const int*)d_in[2];
    const int*   movies= (const int*)d_in[3];
    const float* W1    = (const float*)d_in[4];
    const float* b1    = (const float*)d_in[5];
    const float* W2    = (const float*)d_in[6];
    const float* b2    = (const float*)d_in[7];
    const float* fc_w  = (const float*)d_in[8];
    const float* fc_b  = (const float*)d_in[9];
    float* out = (float*)d_out;

    const int IN_DIM = 128;
    const int n       = in_sizes[0] / IN_DIM;  // 100000
    const int n_edges = in_sizes[1] / 2;       // 1200000
    const int batch   = in_sizes[2];           // 8192

    const int* esrc = edge;
    const int* edst = edge + n_edges;

    float* ws = (float*)d_ws;
    size_t o = 0;
    float* dinv = ws + o;  o += ((size_t)n + 255) & ~(size_t)255;
    float* B    = ws + o;  o += ((size_t)n * HID + 255) & ~(size_t)255;
    float* C    = ws + o;

    const int total = n * HID;   // 6,400,000 (divisible by 4)

    // norm precompute
    deg_init_kernel<<<(n + 255) / 256, 256, 0, stream>>>(dinv, n);
    deg_accum_kernel<<<2048, 256, 0, stream>>>(edst, dinv, n_edges);
    rsqrt_kernel<<<(n + 255) / 256, 256, 0, stream>>>(dinv, n);

    // ---- layer 1 ----
    gemm_scale_kernel<128><<<1024, 256, 0, stream>>>(x, W1, dinv, B, n);   // B = hs1
    copy_kernel<<<2048, 256, 0, stream>>>((const float4*)B, (float4*)C, total / 4); // C = self-loop init
    scatter_kernel<<<2048, 256, 0, stream>>>(B, esrc, edst, C, n_edges);   // C += edges
    bias_relu_kernel<<<2048, 256, 0, stream>>>(C, dinv, b1, B, total);     // B = h1

    // ---- layer 2 ----
    gemm_scale_kernel<64><<<1024, 256, 0, stream>>>(B, W2, dinv, C, n);    // C = hs2
    copy_kernel<<<2048, 256, 0, stream>>>((const float4*)C, (float4*)B, total / 4); // B = self-loop init
    scatter_kernel<<<2048, 256, 0, stream>>>(C, esrc, edst, B, n_edges);   // B += edges
    bias_relu_kernel<<<2048, 256, 0, stream>>>(B, dinv, b2, C, total);     // C = h2

    // ---- prediction head ----
    final_kernel<<<2048, 256, 0, stream>>>(C, users, movies, fc_w, fc_b, out, batch);
}

// Round 2
// 809.214 us; speedup vs baseline: 1.0812x; 1.0812x over previous
//
#include <hip/hip_runtime.h>

#define HID 64

// ---------------- CSR build ----------------
__global__ void zero_int_kernel(int* __restrict__ p, int n) {
    int i = blockIdx.x * blockDim.x + threadIdx.x;
    if (i < n) p[i] = 0;
}

__global__ void deg_count_kernel(const int* __restrict__ dst, int* __restrict__ deg, int n_edges) {
    int i = blockIdx.x * blockDim.x + threadIdx.x;
    int stride = gridDim.x * blockDim.x;
    for (int e = i; e < n_edges; e += stride)
        atomicAdd(&deg[dst[e]], 1);
}

__global__ void dinv_kernel(const int* __restrict__ deg, float* __restrict__ dinv, int n) {
    int i = blockIdx.x * blockDim.x + threadIdx.x;
    if (i < n) dinv[i] = rsqrtf((float)(deg[i] + 1));   // +1 = self-loop
}

// single-workgroup exclusive scan of deg -> row_ptr (and cursor copy)
__global__ void scan_kernel(const int* __restrict__ deg, int* __restrict__ row_ptr,
                            int* __restrict__ cursor, int n) {
    __shared__ int smem[1024];
    __shared__ int s_carry;
    const int tid = threadIdx.x;
    if (tid == 0) s_carry = 0;
    __syncthreads();
    for (int base = 0; base < n; base += 1024) {
        int i = base + tid;
        int v = (i < n) ? deg[i] : 0;
        smem[tid] = v;
        __syncthreads();
#pragma unroll
        for (int off = 1; off < 1024; off <<= 1) {
            int t = (tid >= off) ? smem[tid - off] : 0;
            __syncthreads();
            smem[tid] += t;
            __syncthreads();
        }
        int excl = s_carry + smem[tid] - v;
        if (i < n) { row_ptr[i] = excl; cursor[i] = excl; }
        __syncthreads();
        if (tid == 0) s_carry += smem[1023];
        __syncthreads();
    }
    if (tid == 0) row_ptr[n] = s_carry;
}

__global__ void fill_kernel(const int* __restrict__ src, const int* __restrict__ dst,
                            int* __restrict__ cursor, int* __restrict__ col, int n_edges) {
    int i = blockIdx.x * blockDim.x + threadIdx.x;
    int stride = gridDim.x * blockDim.x;
    for (int e = i; e < n_edges; e += stride) {
        int pos = atomicAdd(&cursor[dst[e]], 1);
        col[pos] = src[e];
    }
}

// ---------------- GEMM: hs[i][c] = dinv[i] * sum_k X[i][k]*W[c][k] ----------------
template<int K>
__global__ void __launch_bounds__(256) gemm_scale_kernel(
    const float* __restrict__ X,     // [n][K]
    const float* __restrict__ W,     // [64][K]
    const float* __restrict__ dinv,  // [n]
    float* __restrict__ out,         // [n][64]
    int n) {
    const int lane = threadIdx.x & 63;
    int wid = blockIdx.x * (blockDim.x >> 6) + (threadIdx.x >> 6);
    const int nw = gridDim.x * (blockDim.x >> 6);

    float w[K];
#pragma unroll
    for (int k = 0; k < K; k += 4) {
        float4 v = *reinterpret_cast<const float4*>(W + lane * K + k);
        w[k] = v.x; w[k + 1] = v.y; w[k + 2] = v.z; w[k + 3] = v.w;
    }

    for (int node = wid; node < n; node += nw) {
        const float* xr = X + (size_t)node * K;
        float a0 = 0.f, a1 = 0.f, a2 = 0.f, a3 = 0.f;
#pragma unroll
        for (int k = 0; k < K; k += 4) {
            float4 v = *reinterpret_cast<const float4*>(xr + k);
            a0 += v.x * w[k];
            a1 += v.y * w[k + 1];
            a2 += v.z * w[k + 2];
            a3 += v.w * w[k + 3];
        }
        out[(size_t)node * HID + lane] = (a0 + a1 + a2 + a3) * dinv[node];
    }
}

// ---------------- fused aggregate: h = relu(dinv*(hs[self] + sum hs[col]) + b) ----------------
__global__ void __launch_bounds__(256) gather_kernel(
    const float* __restrict__ hs, const int* __restrict__ row_ptr, const int* __restrict__ col,
    const float* __restrict__ dinv, const float* __restrict__ b,
    float* __restrict__ out, int n) {
    const int lane = threadIdx.x & 63;
    int wid = blockIdx.x * (blockDim.x >> 6) + (threadIdx.x >> 6);
    const int nw = gridDim.x * (blockDim.x >> 6);
    for (int node = wid; node < n; node += nw) {
        int beg = row_ptr[node];
        int end = row_ptr[node + 1];
        float acc = hs[(size_t)node * HID + lane];    // self-loop
        for (int e = beg; e < end; ++e) {
            int s = col[e];
            acc += hs[(size_t)s * HID + lane];
        }
        float v = dinv[node] * acc + b[lane];
        out[(size_t)node * HID + lane] = v > 0.f ? v : 0.f;
    }
}

// ---------------- scores[p] = sum_c h[u][c]*h[m][c]*fc_w[c] + fc_b ----------------
__global__ void final_kernel(const float* __restrict__ h,
                             const int* __restrict__ users, const int* __restrict__ movies,
                             const float* __restrict__ fc_w, const float* __restrict__ fc_b,
                             float* __restrict__ out, int batch) {
    const int lane = threadIdx.x & 63;
    int wid = blockIdx.x * (blockDim.x >> 6) + (threadIdx.x >> 6);
    const int nw = gridDim.x * (blockDim.x >> 6);
    for (int p = wid; p < batch; p += nw) {
        int u = users[p];
        int m = movies[p];
        float v = h[(size_t)u * HID + lane] * h[(size_t)m * HID + lane] * fc_w[lane];
#pragma unroll
        for (int off = 32; off > 0; off >>= 1)
            v += __shfl_down(v, off, 64);
        if (lane == 0) out[p] = v + fc_b[0];
    }
}

extern "C" void kernel_launch(void* const* d_in, const int* in_sizes, int n_in,
                              void* d_out, int out_size, void* d_ws, size_t ws_size,
                              hipStream_t stream) {
    const float* x     = (const float*)d_in[0];
    const int*   edge  = (const int*)d_in[1];   // [2][E]
    const int*   users = (const int*)d_in[2];
    const int*   movies= (const int*)d_in[3];
    const float* W1    = (const float*)d_in[4];
    const float* b1    = (const float*)d_in[5];
    const float* W2    = (const float*)d_in[6];
    const float* b2    = (const float*)d_in[7];
    const float* fc_w  = (const float*)d_in[8];
    const float* fc_b  = (const float*)d_in[9];
    float* out = (float*)d_out;

    const int IN_DIM = 128;
    const int n       = in_sizes[0] / IN_DIM;  // 100000
    const int n_edges = in_sizes[1] / 2;       // 1200000
    const int batch   = in_sizes[2];           // 8192

    const int* esrc = edge;
    const int* edst = edge + n_edges;

    char* ws = (char*)d_ws;
    size_t o = 0;
    auto alloc = [&](size_t bytes) { void* p = ws + o; o = (o + bytes + 255) & ~(size_t)255; return p; };
    int*   deg     = (int*)  alloc(sizeof(int) * n);
    int*   row_ptr = (int*)  alloc(sizeof(int) * (n + 1));
    int*   cursor  = (int*)  alloc(sizeof(int) * n);
    int*   col     = (int*)  alloc(sizeof(int) * n_edges);
    float* dinv    = (float*)alloc(sizeof(float) * n);
    float* B       = (float*)alloc(sizeof(float) * (size_t)n * HID);
    float* C       = (float*)alloc(sizeof(float) * (size_t)n * HID);

    // ---- CSR build + norm ----
    zero_int_kernel<<<(n + 255) / 256, 256, 0, stream>>>(deg, n);
    deg_count_kernel<<<1024, 256, 0, stream>>>(edst, deg, n_edges);
    dinv_kernel<<<(n + 255) / 256, 256, 0, stream>>>(deg, dinv, n);
    scan_kernel<<<1, 1024, 0, stream>>>(deg, row_ptr, cursor, n);
    fill_kernel<<<1024, 256, 0, stream>>>(esrc, edst, cursor, col, n_edges);

    // ---- layer 1 ----
    gemm_scale_kernel<128><<<1024, 256, 0, stream>>>(x, W1, dinv, B, n);      // B = hs1
    gather_kernel<<<2048, 256, 0, stream>>>(B, row_ptr, col, dinv, b1, C, n); // C = h1

    // ---- layer 2 ----
    gemm_scale_kernel<64><<<1024, 256, 0, stream>>>(C, W2, dinv, B, n);       // B = hs2
    gather_kernel<<<2048, 256, 0, stream>>>(B, row_ptr, col, dinv, b2, C, n); // C = h2

    // ---- prediction head ----
    final_kernel<<<2048, 256, 0, stream>>>(C, users, movies, fc_w, fc_b, out, batch);
}

// Round 3
// 314.569 us; speedup vs baseline: 2.7815x; 2.5724x over previous
//
#include <hip/hip_runtime.h>

#define HID 64

// ---------------- CSR build ----------------
__global__ void zero_int_kernel(int* __restrict__ p, int n) {
    int i = blockIdx.x * blockDim.x + threadIdx.x;
    if (i < n) p[i] = 0;
}

__global__ void deg_count_kernel(const int* __restrict__ dst, int* __restrict__ deg, int n_edges) {
    int i = blockIdx.x * blockDim.x + threadIdx.x;
    int stride = gridDim.x * blockDim.x;
    for (int e = i; e < n_edges; e += stride)
        atomicAdd(&deg[dst[e]], 1);
}

__global__ void dinv_kernel(const int* __restrict__ deg, float* __restrict__ dinv, int n) {
    int i = blockIdx.x * blockDim.x + threadIdx.x;
    if (i < n) dinv[i] = rsqrtf((float)(deg[i] + 1));   // +1 = self-loop
}

// two-level scan: (1) per-1024-block exclusive scan + block sums
__global__ void __launch_bounds__(1024) scan_partial_kernel(
    const int* __restrict__ deg, int* __restrict__ tmp, int* __restrict__ bsum, int n) {
    __shared__ int sm[1024];
    const int tid = threadIdx.x;
    int i = blockIdx.x * 1024 + tid;
    int v = (i < n) ? deg[i] : 0;
    sm[tid] = v;
    __syncthreads();
#pragma unroll
    for (int off = 1; off < 1024; off <<= 1) {
        int t = (tid >= off) ? sm[tid - off] : 0;
        __syncthreads();
        sm[tid] += t;
        __syncthreads();
    }
    if (i < n) tmp[i] = sm[tid] - v;          // exclusive within block
    if (tid == 1023) bsum[blockIdx.x] = sm[1023];
}

// (2) scan the (<=128) block sums in one small block; boff[128] = grand total
__global__ void __launch_bounds__(128) scan_sums_kernel(
    const int* __restrict__ bsum, int* __restrict__ boff, int nb) {
    __shared__ int sm[128];
    const int tid = threadIdx.x;
    int v = (tid < nb) ? bsum[tid] : 0;
    sm[tid] = v;
    __syncthreads();
#pragma unroll
    for (int off = 1; off < 128; off <<= 1) {
        int t = (tid >= off) ? sm[tid - off] : 0;
        __syncthreads();
        sm[tid] += t;
        __syncthreads();
    }
    boff[tid] = sm[tid] - v;                  // exclusive
    if (tid == 127) boff[128] = sm[127];      // total
}

// (3) add block offsets -> row_ptr & cursor
__global__ void finalize_rowptr_kernel(const int* __restrict__ tmp, const int* __restrict__ boff,
                                       int* __restrict__ row_ptr, int* __restrict__ cursor, int n) {
    int i = blockIdx.x * blockDim.x + threadIdx.x;
    if (i < n) {
        int v = tmp[i] + boff[i >> 10];
        row_ptr[i] = v;
        cursor[i] = v;
    }
    if (i == n) row_ptr[n] = boff[128];
}

__global__ void fill_kernel(const int* __restrict__ src, const int* __restrict__ dst,
                            int* __restrict__ cursor, int* __restrict__ col, int n_edges) {
    int i = blockIdx.x * blockDim.x + threadIdx.x;
    int stride = gridDim.x * blockDim.x;
    for (int e = i; e < n_edges; e += stride) {
        int pos = atomicAdd(&cursor[dst[e]], 1);
        col[pos] = src[e];
    }
}

// ---------------- tiled GEMM: hs[i][c] = dinv[i] * sum_k X[i][k]*W[c][k] ----------------
// BM=64 nodes x BN=64 ch x BK=32, 256 threads, 4x4 register tile per thread.
template<int K>
__global__ void __launch_bounds__(256) gemm_tile_kernel(
    const float* __restrict__ X,     // [n][K]
    const float* __restrict__ W,     // [64][K]
    const float* __restrict__ dinv,  // [n]
    float* __restrict__ out,         // [n][64]
    int n) {
    constexpr int BK = 32;
    constexpr int NKB = K / BK;
    __shared__ float As[BK][68];   // As[k][m], padded, rows 16B-aligned
    __shared__ float Bs[BK][68];   // Bs[k][c]

    const int t = threadIdx.x;
    const int mbase = blockIdx.x * 64;
    const int tc = t & 15;         // channel tile 0..15
    const int tm = t >> 4;         // node tile 0..15
    const int lr = t >> 3;         // staging row 0..31
    const int k4 = (t & 7) * 4;    // staging k offset

    float acc[4][4] = {};

    for (int kb = 0; kb < NKB; ++kb) {
        __syncthreads();
#pragma unroll
        for (int h = 0; h < 2; ++h) {
            int m = lr + h * 32;
            int node = mbase + m;
            float4 v = make_float4(0.f, 0.f, 0.f, 0.f);
            if (node < n)
                v = *reinterpret_cast<const float4*>(X + (size_t)node * K + kb * BK + k4);
            As[k4 + 0][m] = v.x; As[k4 + 1][m] = v.y;
            As[k4 + 2][m] = v.z; As[k4 + 3][m] = v.w;

            int c = m;   // 64 channels
            float4 wv = *reinterpret_cast<const float4*>(W + (size_t)c * K + kb * BK + k4);
            Bs[k4 + 0][c] = wv.x; Bs[k4 + 1][c] = wv.y;
            Bs[k4 + 2][c] = wv.z; Bs[k4 + 3][c] = wv.w;
        }
        __syncthreads();
#pragma unroll
        for (int k = 0; k < BK; ++k) {
            float4 a = *reinterpret_cast<const float4*>(&As[k][tm * 4]);
            float4 b = *reinterpret_cast<const float4*>(&Bs[k][tc * 4]);
            acc[0][0] += a.x * b.x; acc[0][1] += a.x * b.y; acc[0][2] += a.x * b.z; acc[0][3] += a.x * b.w;
            acc[1][0] += a.y * b.x; acc[1][1] += a.y * b.y; acc[1][2] += a.y * b.z; acc[1][3] += a.y * b.w;
            acc[2][0] += a.z * b.x; acc[2][1] += a.z * b.y; acc[2][2] += a.z * b.z; acc[2][3] += a.z * b.w;
            acc[3][0] += a.w * b.x; acc[3][1] += a.w * b.y; acc[3][2] += a.w * b.z; acc[3][3] += a.w * b.w;
        }
    }

#pragma unroll
    for (int i = 0; i < 4; ++i) {
        int node = mbase + tm * 4 + i;
        if (node < n) {
            float s = dinv[node];
            float4 o = make_float4(acc[i][0] * s, acc[i][1] * s, acc[i][2] * s, acc[i][3] * s);
            *reinterpret_cast<float4*>(out + (size_t)node * HID + tc * 4) = o;
        }
    }
}

// ---------------- fused aggregate: h = relu(dinv*(hs[self] + sum hs[col]) + b) ----------------
__global__ void __launch_bounds__(256) gather_kernel(
    const float* __restrict__ hs, const int* __restrict__ row_ptr, const int* __restrict__ col,
    const float* __restrict__ dinv, const float* __restrict__ b,
    float* __restrict__ out, int n) {
    const int lane = threadIdx.x & 63;
    int wid = blockIdx.x * (blockDim.x >> 6) + (threadIdx.x >> 6);
    const int nw = gridDim.x * (blockDim.x >> 6);
    for (int node = wid; node < n; node += nw) {
        int beg = __builtin_amdgcn_readfirstlane(row_ptr[node]);
        int end = __builtin_amdgcn_readfirstlane(row_ptr[node + 1]);
        float acc0 = hs[(size_t)node * HID + lane];   // self-loop
        float acc1 = 0.f, acc2 = 0.f, acc3 = 0.f;
        int e = beg;
        for (; e + 4 <= end; e += 4) {
            int s0 = col[e], s1 = col[e + 1], s2 = col[e + 2], s3 = col[e + 3];
            acc0 += hs[(size_t)s0 * HID + lane];
            acc1 += hs[(size_t)s1 * HID + lane];
            acc2 += hs[(size_t)s2 * HID + lane];
            acc3 += hs[(size_t)s3 * HID + lane];
        }
        for (; e < end; ++e)
            acc0 += hs[(size_t)col[e] * HID + lane];
        float v = dinv[node] * ((acc0 + acc1) + (acc2 + acc3)) + b[lane];
        out[(size_t)node * HID + lane] = v > 0.f ? v : 0.f;
    }
}

// ---------------- scores[p] = sum_c h[u][c]*h[m][c]*fc_w[c] + fc_b ----------------
__global__ void final_kernel(const float* __restrict__ h,
                             const int* __restrict__ users, const int* __restrict__ movies,
                             const float* __restrict__ fc_w, const float* __restrict__ fc_b,
                             float* __restrict__ out, int batch) {
    const int lane = threadIdx.x & 63;
    int wid = blockIdx.x * (blockDim.x >> 6) + (threadIdx.x >> 6);
    const int nw = gridDim.x * (blockDim.x >> 6);
    for (int p = wid; p < batch; p += nw) {
        int u = users[p];
        int m = movies[p];
        float v = h[(size_t)u * HID + lane] * h[(size_t)m * HID + lane] * fc_w[lane];
#pragma unroll
        for (int off = 32; off > 0; off >>= 1)
            v += __shfl_down(v, off, 64);
        if (lane == 0) out[p] = v + fc_b[0];
    }
}

extern "C" void kernel_launch(void* const* d_in, const int* in_sizes, int n_in,
                              void* d_out, int out_size, void* d_ws, size_t ws_size,
                              hipStream_t stream) {
    const float* x     = (const float*)d_in[0];
    const int*   edge  = (const int*)d_in[1];   // [2][E]
    const int*   users = (const int*)d_in[2];
    const int*   movies= (const int*)d_in[3];
    const float* W1    = (const float*)d_in[4];
    const float* b1    = (const float*)d_in[5];
    const float* W2    = (const float*)d_in[6];
    const float* b2    = (const float*)d_in[7];
    const float* fc_w  = (const float*)d_in[8];
    const float* fc_b  = (const float*)d_in[9];
    float* out = (float*)d_out;

    const int IN_DIM = 128;
    const int n       = in_sizes[0] / IN_DIM;  // 100000
    const int n_edges = in_sizes[1] / 2;       // 1200000
    const int batch   = in_sizes[2];           // 8192

    const int* esrc = edge;
    const int* edst = edge + n_edges;

    char* ws = (char*)d_ws;
    size_t o = 0;
    auto alloc = [&](size_t bytes) { void* p = ws + o; o = (o + bytes + 255) & ~(size_t)255; return p; };
    int*   deg     = (int*)  alloc(sizeof(int) * n);
    int*   tmp     = (int*)  alloc(sizeof(int) * n);
    int*   bsum    = (int*)  alloc(sizeof(int) * 128);
    int*   boff    = (int*)  alloc(sizeof(int) * 129);
    int*   row_ptr = (int*)  alloc(sizeof(int) * (n + 1));
    int*   cursor  = (int*)  alloc(sizeof(int) * n);
    int*   col     = (int*)  alloc(sizeof(int) * n_edges);
    float* dinv    = (float*)alloc(sizeof(float) * n);
    float* B       = (float*)alloc(sizeof(float) * (size_t)n * HID);
    float* C       = (float*)alloc(sizeof(float) * (size_t)n * HID);

    const int nb1024 = (n + 1023) / 1024;      // 98 (<=128)

    // ---- CSR build + norm ----
    zero_int_kernel<<<(n + 255) / 256, 256, 0, stream>>>(deg, n);
    deg_count_kernel<<<1024, 256, 0, stream>>>(edst, deg, n_edges);
    dinv_kernel<<<(n + 255) / 256, 256, 0, stream>>>(deg, dinv, n);
    scan_partial_kernel<<<nb1024, 1024, 0, stream>>>(deg, tmp, bsum, n);
    scan_sums_kernel<<<1, 128, 0, stream>>>(bsum, boff, nb1024);
    finalize_rowptr_kernel<<<(n + 256) / 256, 256, 0, stream>>>(tmp, boff, row_ptr, cursor, n);
    fill_kernel<<<1024, 256, 0, stream>>>(esrc, edst, cursor, col, n_edges);

    // ---- layer 1 ----
    gemm_tile_kernel<128><<<(n + 63) / 64, 256, 0, stream>>>(x, W1, dinv, B, n);   // B = hs1
    gather_kernel<<<2048, 256, 0, stream>>>(B, row_ptr, col, dinv, b1, C, n);      // C = h1

    // ---- layer 2 ----
    gemm_tile_kernel<64><<<(n + 63) / 64, 256, 0, stream>>>(C, W2, dinv, B, n);    // B = hs2
    gather_kernel<<<2048, 256, 0, stream>>>(B, row_ptr, col, dinv, b2, C, n);      // C = h2

    // ---- prediction head ----
    final_kernel<<<2048, 256, 0, stream>>>(C, users, movies, fc_w, fc_b, out, batch);
}

// Round 4
// 234.622 us; speedup vs baseline: 3.7292x; 1.3407x over previous
//
#include <hip/hip_runtime.h>

#define HID 64

// ---------------- CSR build ----------------
__global__ void zero_int_kernel(int* __restrict__ p, int n) {
    int i = blockIdx.x * blockDim.x + threadIdx.x;
    if (i < n) p[i] = 0;
}

// pass A: count degrees AND record each edge's rank within its dst segment
__global__ void count_rel_kernel(const int* __restrict__ dst, int* __restrict__ deg,
                                 int* __restrict__ rel, int n_edges) {
    int e = blockIdx.x * blockDim.x + threadIdx.x;
    if (e < n_edges) rel[e] = atomicAdd(&deg[dst[e]], 1);
}

__global__ void dinv_kernel(const int* __restrict__ deg, float* __restrict__ dinv, int n) {
    int i = blockIdx.x * blockDim.x + threadIdx.x;
    if (i < n) dinv[i] = rsqrtf((float)(deg[i] + 1));   // +1 = self-loop
}

// two-level scan: (1) per-1024-block exclusive scan + block sums
__global__ void __launch_bounds__(1024) scan_partial_kernel(
    const int* __restrict__ deg, int* __restrict__ tmp, int* __restrict__ bsum, int n) {
    __shared__ int sm[1024];
    const int tid = threadIdx.x;
    int i = blockIdx.x * 1024 + tid;
    int v = (i < n) ? deg[i] : 0;
    sm[tid] = v;
    __syncthreads();
#pragma unroll
    for (int off = 1; off < 1024; off <<= 1) {
        int t = (tid >= off) ? sm[tid - off] : 0;
        __syncthreads();
        sm[tid] += t;
        __syncthreads();
    }
    if (i < n) tmp[i] = sm[tid] - v;          // exclusive within block
    if (tid == 1023) bsum[blockIdx.x] = sm[1023];
}

// (2) scan the (<=128) block sums; boff[128] = grand total
__global__ void __launch_bounds__(128) scan_sums_kernel(
    const int* __restrict__ bsum, int* __restrict__ boff, int nb) {
    __shared__ int sm[128];
    const int tid = threadIdx.x;
    int v = (tid < nb) ? bsum[tid] : 0;
    sm[tid] = v;
    __syncthreads();
#pragma unroll
    for (int off = 1; off < 128; off <<= 1) {
        int t = (tid >= off) ? sm[tid - off] : 0;
        __syncthreads();
        sm[tid] += t;
        __syncthreads();
    }
    boff[tid] = sm[tid] - v;                  // exclusive
    if (tid == 127) boff[128] = sm[127];      // total
}

// (3) add block offsets -> row_ptr
__global__ void finalize_rowptr_kernel(const int* __restrict__ tmp, const int* __restrict__ boff,
                                       int* __restrict__ row_ptr, int n) {
    int i = blockIdx.x * blockDim.x + threadIdx.x;
    if (i < n) row_ptr[i] = tmp[i] + boff[i >> 10];
    if (i == n) row_ptr[n] = boff[128];
}

// pass B: atomic-free CSR fill
__global__ void fill2_kernel(const int* __restrict__ src, const int* __restrict__ dst,
                             const int* __restrict__ row_ptr, const int* __restrict__ rel,
                             int* __restrict__ col, int n_edges) {
    int e = blockIdx.x * blockDim.x + threadIdx.x;
    if (e < n_edges) col[row_ptr[dst[e]] + rel[e]] = src[e];
}

// ---------------- tiled GEMM: hs[i][c] = dinv[i] * sum_k X[i][k]*W[c][k] ----------------
// BM=64 nodes x BN=64 ch x BK=32, 256 threads, 4x4 register tile per thread.
template<int K>
__global__ void __launch_bounds__(256) gemm_tile_kernel(
    const float* __restrict__ X,     // [n][K]
    const float* __restrict__ W,     // [64][K]
    const float* __restrict__ dinv,  // [n]
    float* __restrict__ out,         // [n][64]
    int n) {
    constexpr int BK = 32;
    constexpr int NKB = K / BK;
    __shared__ float As[BK][68];   // As[k][m], padded
    __shared__ float Bs[BK][68];   // Bs[k][c]

    const int t = threadIdx.x;
    const int mbase = blockIdx.x * 64;
    const int tc = t & 15;         // channel tile 0..15
    const int tm = t >> 4;         // node tile 0..15
    const int lr = t >> 3;         // staging row 0..31
    const int k4 = (t & 7) * 4;    // staging k offset

    float acc[4][4] = {};

    for (int kb = 0; kb < NKB; ++kb) {
        __syncthreads();
#pragma unroll
        for (int h = 0; h < 2; ++h) {
            int m = lr + h * 32;
            int node = mbase + m;
            float4 v = make_float4(0.f, 0.f, 0.f, 0.f);
            if (node < n)
                v = *reinterpret_cast<const float4*>(X + (size_t)node * K + kb * BK + k4);
            As[k4 + 0][m] = v.x; As[k4 + 1][m] = v.y;
            As[k4 + 2][m] = v.z; As[k4 + 3][m] = v.w;

            int c = m;   // 64 channels
            float4 wv = *reinterpret_cast<const float4*>(W + (size_t)c * K + kb * BK + k4);
            Bs[k4 + 0][c] = wv.x; Bs[k4 + 1][c] = wv.y;
            Bs[k4 + 2][c] = wv.z; Bs[k4 + 3][c] = wv.w;
        }
        __syncthreads();
#pragma unroll
        for (int k = 0; k < BK; ++k) {
            float4 a = *reinterpret_cast<const float4*>(&As[k][tm * 4]);
            float4 b = *reinterpret_cast<const float4*>(&Bs[k][tc * 4]);
            acc[0][0] += a.x * b.x; acc[0][1] += a.x * b.y; acc[0][2] += a.x * b.z; acc[0][3] += a.x * b.w;
            acc[1][0] += a.y * b.x; acc[1][1] += a.y * b.y; acc[1][2] += a.y * b.z; acc[1][3] += a.y * b.w;
            acc[2][0] += a.z * b.x; acc[2][1] += a.z * b.y; acc[2][2] += a.z * b.z; acc[2][3] += a.z * b.w;
            acc[3][0] += a.w * b.x; acc[3][1] += a.w * b.y; acc[3][2] += a.w * b.z; acc[3][3] += a.w * b.w;
        }
    }

#pragma unroll
    for (int i = 0; i < 4; ++i) {
        int node = mbase + tm * 4 + i;
        if (node < n) {
            float s = dinv[node];
            float4 o = make_float4(acc[i][0] * s, acc[i][1] * s, acc[i][2] * s, acc[i][3] * s);
            *reinterpret_cast<float4*>(out + (size_t)node * HID + tc * 4) = o;
        }
    }
}

// ---------------- fused aggregate: h = relu(dinv*(hs[self] + sum hs[col]) + b) ----------------
// 4 nodes per wave, 16 lanes x float4 per node, unroll-4 edge streams.
__global__ void __launch_bounds__(256) gather_kernel(
    const float* __restrict__ hs, const int* __restrict__ row_ptr, const int* __restrict__ col,
    const float* __restrict__ dinv, const float* __restrict__ b,
    float* __restrict__ out, int n) {
    const float4* __restrict__ hs4 = (const float4*)hs;
    const float4* __restrict__ b4v = (const float4*)b;

    const int lane = threadIdx.x & 63;
    const int sub = lane >> 4;        // node slot 0..3
    const int cl  = lane & 15;        // float4 channel group
    int wid = blockIdx.x * (blockDim.x >> 6) + (threadIdx.x >> 6);
    const int nw = gridDim.x * (blockDim.x >> 6);
    const int ngroups = (n + 3) >> 2;

    const float4 bv = b4v[cl];

    for (int g = wid; g < ngroups; g += nw) {
        int node = g * 4 + sub;
        if (node >= n) continue;
        int beg = row_ptr[node];
        int end = row_ptr[node + 1];

        float4 a0 = hs4[(size_t)node * 16 + cl];   // self-loop
        float4 a1 = make_float4(0.f, 0.f, 0.f, 0.f);
        float4 a2 = make_float4(0.f, 0.f, 0.f, 0.f);
        float4 a3 = make_float4(0.f, 0.f, 0.f, 0.f);

        int e = beg;
        for (; e + 4 <= end; e += 4) {
            int s0 = col[e], s1 = col[e + 1], s2 = col[e + 2], s3 = col[e + 3];
            float4 v0 = hs4[(size_t)s0 * 16 + cl];
            float4 v1 = hs4[(size_t)s1 * 16 + cl];
            float4 v2 = hs4[(size_t)s2 * 16 + cl];
            float4 v3 = hs4[(size_t)s3 * 16 + cl];
            a0.x += v0.x; a0.y += v0.y; a0.z += v0.z; a0.w += v0.w;
            a1.x += v1.x; a1.y += v1.y; a1.z += v1.z; a1.w += v1.w;
            a2.x += v2.x; a2.y += v2.y; a2.z += v2.z; a2.w += v2.w;
            a3.x += v3.x; a3.y += v3.y; a3.z += v3.z; a3.w += v3.w;
        }
        for (; e < end; ++e) {
            float4 v = hs4[(size_t)col[e] * 16 + cl];
            a0.x += v.x; a0.y += v.y; a0.z += v.z; a0.w += v.w;
        }

        float s = dinv[node];
        float4 r;
        r.x = s * ((a0.x + a1.x) + (a2.x + a3.x)) + bv.x;
        r.y = s * ((a0.y + a1.y) + (a2.y + a3.y)) + bv.y;
        r.z = s * ((a0.z + a1.z) + (a2.z + a3.z)) + bv.z;
        r.w = s * ((a0.w + a1.w) + (a2.w + a3.w)) + bv.w;
        r.x = r.x > 0.f ? r.x : 0.f;
        r.y = r.y > 0.f ? r.y : 0.f;
        r.z = r.z > 0.f ? r.z : 0.f;
        r.w = r.w > 0.f ? r.w : 0.f;
        *((float4*)out + (size_t)node * 16 + cl) = r;
    }
}

// ---------------- scores[p] = sum_c h[u][c]*h[m][c]*fc_w[c] + fc_b ----------------
__global__ void final_kernel(const float* __restrict__ h,
                             const int* __restrict__ users, const int* __restrict__ movies,
                             const float* __restrict__ fc_w, const float* __restrict__ fc_b,
                             float* __restrict__ out, int batch) {
    const int lane = threadIdx.x & 63;
    int wid = blockIdx.x * (blockDim.x >> 6) + (threadIdx.x >> 6);
    const int nw = gridDim.x * (blockDim.x >> 6);
    for (int p = wid; p < batch; p += nw) {
        int u = users[p];
        int m = movies[p];
        float v = h[(size_t)u * HID + lane] * h[(size_t)m * HID + lane] * fc_w[lane];
#pragma unroll
        for (int off = 32; off > 0; off >>= 1)
            v += __shfl_down(v, off, 64);
        if (lane == 0) out[p] = v + fc_b[0];
    }
}

extern "C" void kernel_launch(void* const* d_in, const int* in_sizes, int n_in,
                              void* d_out, int out_size, void* d_ws, size_t ws_size,
                              hipStream_t stream) {
    const float* x     = (const float*)d_in[0];
    const int*   edge  = (const int*)d_in[1];   // [2][E]
    const int*   users = (const int*)d_in[2];
    const int*   movies= (const int*)d_in[3];
    const float* W1    = (const float*)d_in[4];
    const float* b1    = (const float*)d_in[5];
    const float* W2    = (const float*)d_in[6];
    const float* b2    = (const float*)d_in[7];
    const float* fc_w  = (const float*)d_in[8];
    const float* fc_b  = (const float*)d_in[9];
    float* out = (float*)d_out;

    const int IN_DIM = 128;
    const int n       = in_sizes[0] / IN_DIM;  // 100000
    const int n_edges = in_sizes[1] / 2;       // 1200000
    const int batch   = in_sizes[2];           // 8192

    const int* esrc = edge;
    const int* edst = edge + n_edges;

    char* ws = (char*)d_ws;
    size_t o = 0;
    auto alloc = [&](size_t bytes) { void* p = ws + o; o = (o + bytes + 255) & ~(size_t)255; return p; };
    int*   deg     = (int*)  alloc(sizeof(int) * n);
    int*   tmp     = (int*)  alloc(sizeof(int) * n);
    int*   bsum    = (int*)  alloc(sizeof(int) * 128);
    int*   boff    = (int*)  alloc(sizeof(int) * 129);
    int*   row_ptr = (int*)  alloc(sizeof(int) * (n + 1));
    int*   rel     = (int*)  alloc(sizeof(int) * n_edges);
    int*   col     = (int*)  alloc(sizeof(int) * n_edges);
    float* dinv    = (float*)alloc(sizeof(float) * n);
    float* B       = (float*)alloc(sizeof(float) * (size_t)n * HID);
    float* C       = (float*)alloc(sizeof(float) * (size_t)n * HID);

    const int nb1024 = (n + 1023) / 1024;      // 98 (<=128)
    const int epb    = (n_edges + 255) / 256;  // one thread per edge

    // ---- CSR build + norm ----
    zero_int_kernel<<<(n + 255) / 256, 256, 0, stream>>>(deg, n);
    count_rel_kernel<<<epb, 256, 0, stream>>>(edst, deg, rel, n_edges);
    dinv_kernel<<<(n + 255) / 256, 256, 0, stream>>>(deg, dinv, n);
    scan_partial_kernel<<<nb1024, 1024, 0, stream>>>(deg, tmp, bsum, n);
    scan_sums_kernel<<<1, 128, 0, stream>>>(bsum, boff, nb1024);
    finalize_rowptr_kernel<<<(n + 256) / 256, 256, 0, stream>>>(tmp, boff, row_ptr, n);
    fill2_kernel<<<epb, 256, 0, stream>>>(esrc, edst, row_ptr, rel, col, n_edges);

    // ---- layer 1 ----
    gemm_tile_kernel<128><<<(n + 63) / 64, 256, 0, stream>>>(x, W1, dinv, B, n);   // B = hs1
    gather_kernel<<<2048, 256, 0, stream>>>(B, row_ptr, col, dinv, b1, C, n);      // C = h1

    // ---- layer 2 ----
    gemm_tile_kernel<64><<<(n + 63) / 64, 256, 0, stream>>>(C, W2, dinv, B, n);    // B = hs2
    gather_kernel<<<2048, 256, 0, stream>>>(B, row_ptr, col, dinv, b2, C, n);      // C = h2

    // ---- prediction head ----
    final_kernel<<<2048, 256, 0, stream>>>(C, users, movies, fc_w, fc_b, out, batch);
}

// Round 5
// 234.038 us; speedup vs baseline: 3.7385x; 1.0025x over previous
//
#include <hip/hip_runtime.h>

#define HID 64

// ---------------- CSR build ----------------
__global__ void zero_int_kernel(int* __restrict__ p, int n) {
    int i = blockIdx.x * blockDim.x + threadIdx.x;
    if (i < n) p[i] = 0;
}

// pass A: count degrees AND record each edge's rank within its dst segment.
// int4 per thread: 4 independent atomics in flight per lane.
__global__ void count_rel_kernel(const int4* __restrict__ dst4, int* __restrict__ deg,
                                 int4* __restrict__ rel4, int n4) {
    int j = blockIdx.x * blockDim.x + threadIdx.x;
    if (j < n4) {
        int4 d = dst4[j];
        int4 r;
        r.x = atomicAdd(&deg[d.x], 1);
        r.y = atomicAdd(&deg[d.y], 1);
        r.z = atomicAdd(&deg[d.z], 1);
        r.w = atomicAdd(&deg[d.w], 1);
        rel4[j] = r;
    }
}

// two-level scan: (1) per-1024-block exclusive scan + block sums
__global__ void __launch_bounds__(1024) scan_partial_kernel(
    const int* __restrict__ deg, int* __restrict__ tmp, int* __restrict__ bsum, int n) {
    __shared__ int sm[1024];
    const int tid = threadIdx.x;
    int i = blockIdx.x * 1024 + tid;
    int v = (i < n) ? deg[i] : 0;
    sm[tid] = v;
    __syncthreads();
#pragma unroll
    for (int off = 1; off < 1024; off <<= 1) {
        int t = (tid >= off) ? sm[tid - off] : 0;
        __syncthreads();
        sm[tid] += t;
        __syncthreads();
    }
    if (i < n) tmp[i] = sm[tid] - v;          // exclusive within block
    if (tid == 1023) bsum[blockIdx.x] = sm[1023];
}

// (2) scan the (<=128) block sums; boff[128] = grand total
__global__ void __launch_bounds__(128) scan_sums_kernel(
    const int* __restrict__ bsum, int* __restrict__ boff, int nb) {
    __shared__ int sm[128];
    const int tid = threadIdx.x;
    int v = (tid < nb) ? bsum[tid] : 0;
    sm[tid] = v;
    __syncthreads();
#pragma unroll
    for (int off = 1; off < 128; off <<= 1) {
        int t = (tid >= off) ? sm[tid - off] : 0;
        __syncthreads();
        sm[tid] += t;
        __syncthreads();
    }
    boff[tid] = sm[tid] - v;                  // exclusive
    if (tid == 127) boff[128] = sm[127];      // total
}

// (3) add block offsets -> row_ptr; fused dinv = rsqrt(deg+1)
__global__ void finalize_rowptr_kernel(const int* __restrict__ tmp, const int* __restrict__ boff,
                                       const int* __restrict__ deg,
                                       int* __restrict__ row_ptr, float* __restrict__ dinv, int n) {
    int i = blockIdx.x * blockDim.x + threadIdx.x;
    if (i < n) {
        row_ptr[i] = tmp[i] + boff[i >> 10];
        dinv[i] = rsqrtf((float)(deg[i] + 1));   // +1 = self-loop
    }
    if (i == n) row_ptr[n] = boff[128];
}

// pass B: atomic-free CSR fill, int4 per thread (4 independent chains)
__global__ void fill2_kernel(const int4* __restrict__ src4, const int4* __restrict__ dst4,
                             const int* __restrict__ row_ptr, const int4* __restrict__ rel4,
                             int* __restrict__ col, int n4) {
    int j = blockIdx.x * blockDim.x + threadIdx.x;
    if (j < n4) {
        int4 d = dst4[j];
        int4 r = rel4[j];
        int4 s = src4[j];
        col[row_ptr[d.x] + r.x] = s.x;
        col[row_ptr[d.y] + r.y] = s.y;
        col[row_ptr[d.z] + r.z] = s.z;
        col[row_ptr[d.w] + r.w] = s.w;
    }
}

// ---------------- tiled GEMM: hs[i][c] = dinv[i] * sum_k X[i][k]*W[c][k] ----------------
// BM=64 nodes x BN=64 ch x BK=32, 256 threads, 4x4 register tile per thread.
template<int K>
__global__ void __launch_bounds__(256) gemm_tile_kernel(
    const float* __restrict__ X,     // [n][K]
    const float* __restrict__ W,     // [64][K]
    const float* __restrict__ dinv,  // [n]
    float* __restrict__ out,         // [n][64]
    int n) {
    constexpr int BK = 32;
    constexpr int NKB = K / BK;
    __shared__ float As[BK][68];   // As[k][m], padded
    __shared__ float Bs[BK][68];   // Bs[k][c]

    const int t = threadIdx.x;
    const int mbase = blockIdx.x * 64;
    const int tc = t & 15;         // channel tile 0..15
    const int tm = t >> 4;         // node tile 0..15
    const int lr = t >> 3;         // staging row 0..31
    const int k4 = (t & 7) * 4;    // staging k offset

    float acc[4][4] = {};

    for (int kb = 0; kb < NKB; ++kb) {
        __syncthreads();
#pragma unroll
        for (int h = 0; h < 2; ++h) {
            int m = lr + h * 32;
            int node = mbase + m;
            float4 v = make_float4(0.f, 0.f, 0.f, 0.f);
            if (node < n)
                v = *reinterpret_cast<const float4*>(X + (size_t)node * K + kb * BK + k4);
            As[k4 + 0][m] = v.x; As[k4 + 1][m] = v.y;
            As[k4 + 2][m] = v.z; As[k4 + 3][m] = v.w;

            int c = m;   // 64 channels
            float4 wv = *reinterpret_cast<const float4*>(W + (size_t)c * K + kb * BK + k4);
            Bs[k4 + 0][c] = wv.x; Bs[k4 + 1][c] = wv.y;
            Bs[k4 + 2][c] = wv.z; Bs[k4 + 3][c] = wv.w;
        }
        __syncthreads();
#pragma unroll
        for (int k = 0; k < BK; ++k) {
            float4 a = *reinterpret_cast<const float4*>(&As[k][tm * 4]);
            float4 b = *reinterpret_cast<const float4*>(&Bs[k][tc * 4]);
            acc[0][0] += a.x * b.x; acc[0][1] += a.x * b.y; acc[0][2] += a.x * b.z; acc[0][3] += a.x * b.w;
            acc[1][0] += a.y * b.x; acc[1][1] += a.y * b.y; acc[1][2] += a.y * b.z; acc[1][3] += a.y * b.w;
            acc[2][0] += a.z * b.x; acc[2][1] += a.z * b.y; acc[2][2] += a.z * b.z; acc[2][3] += a.z * b.w;
            acc[3][0] += a.w * b.x; acc[3][1] += a.w * b.y; acc[3][2] += a.w * b.z; acc[3][3] += a.w * b.w;
        }
    }

#pragma unroll
    for (int i = 0; i < 4; ++i) {
        int node = mbase + tm * 4 + i;
        if (node < n) {
            float s = dinv[node];
            float4 o = make_float4(acc[i][0] * s, acc[i][1] * s, acc[i][2] * s, acc[i][3] * s);
            *reinterpret_cast<float4*>(out + (size_t)node * HID + tc * 4) = o;
        }
    }
}

// ---------------- fused aggregate: h = relu(dinv*(hs[self] + sum hs[col]) + b) ----------------
// 4 nodes per wave, 16 lanes x float4 per node, unroll-4 edge streams.
__global__ void __launch_bounds__(256) gather_kernel(
    const float* __restrict__ hs, const int* __restrict__ row_ptr, const int* __restrict__ col,
    const float* __restrict__ dinv, const float* __restrict__ b,
    float* __restrict__ out, int n) {
    const float4* __restrict__ hs4 = (const float4*)hs;
    const float4* __restrict__ b4v = (const float4*)b;

    const int lane = threadIdx.x & 63;
    const int sub = lane >> 4;        // node slot 0..3
    const int cl  = lane & 15;        // float4 channel group
    int wid = blockIdx.x * (blockDim.x >> 6) + (threadIdx.x >> 6);
    const int nw = gridDim.x * (blockDim.x >> 6);
    const int ngroups = (n + 3) >> 2;

    const float4 bv = b4v[cl];

    for (int g = wid; g < ngroups; g += nw) {
        int node = g * 4 + sub;
        if (node >= n) continue;
        int beg = row_ptr[node];
        int end = row_ptr[node + 1];

        float4 a0 = hs4[(size_t)node * 16 + cl];   // self-loop
        float4 a1 = make_float4(0.f, 0.f, 0.f, 0.f);
        float4 a2 = make_float4(0.f, 0.f, 0.f, 0.f);
        float4 a3 = make_float4(0.f, 0.f, 0.f, 0.f);

        int e = beg;
        for (; e + 4 <= end; e += 4) {
            int s0 = col[e], s1 = col[e + 1], s2 = col[e + 2], s3 = col[e + 3];
            float4 v0 = hs4[(size_t)s0 * 16 + cl];
            float4 v1 = hs4[(size_t)s1 * 16 + cl];
            float4 v2 = hs4[(size_t)s2 * 16 + cl];
            float4 v3 = hs4[(size_t)s3 * 16 + cl];
            a0.x += v0.x; a0.y += v0.y; a0.z += v0.z; a0.w += v0.w;
            a1.x += v1.x; a1.y += v1.y; a1.z += v1.z; a1.w += v1.w;
            a2.x += v2.x; a2.y += v2.y; a2.z += v2.z; a2.w += v2.w;
            a3.x += v3.x; a3.y += v3.y; a3.z += v3.z; a3.w += v3.w;
        }
        for (; e < end; ++e) {
            float4 v = hs4[(size_t)col[e] * 16 + cl];
            a0.x += v.x; a0.y += v.y; a0.z += v.z; a0.w += v.w;
        }

        float s = dinv[node];
        float4 r;
        r.x = s * ((a0.x + a1.x) + (a2.x + a3.x)) + bv.x;
        r.y = s * ((a0.y + a1.y) + (a2.y + a3.y)) + bv.y;
        r.z = s * ((a0.z + a1.z) + (a2.z + a3.z)) + bv.z;
        r.w = s * ((a0.w + a1.w) + (a2.w + a3.w)) + bv.w;
        r.x = r.x > 0.f ? r.x : 0.f;
        r.y = r.y > 0.f ? r.y : 0.f;
        r.z = r.z > 0.f ? r.z : 0.f;
        r.w = r.w > 0.f ? r.w : 0.f;
        *((float4*)out + (size_t)node * 16 + cl) = r;
    }
}

// ---------------- scores[p] = sum_c h[u][c]*h[m][c]*fc_w[c] + fc_b ----------------
__global__ void final_kernel(const float* __restrict__ h,
                             const int* __restrict__ users, const int* __restrict__ movies,
                             const float* __restrict__ fc_w, const float* __restrict__ fc_b,
                             float* __restrict__ out, int batch) {
    const int lane = threadIdx.x & 63;
    int wid = blockIdx.x * (blockDim.x >> 6) + (threadIdx.x >> 6);
    const int nw = gridDim.x * (blockDim.x >> 6);
    for (int p = wid; p < batch; p += nw) {
        int u = users[p];
        int m = movies[p];
        float v = h[(size_t)u * HID + lane] * h[(size_t)m * HID + lane] * fc_w[lane];
#pragma unroll
        for (int off = 32; off > 0; off >>= 1)
            v += __shfl_down(v, off, 64);
        if (lane == 0) out[p] = v + fc_b[0];
    }
}

extern "C" void kernel_launch(void* const* d_in, const int* in_sizes, int n_in,
                              void* d_out, int out_size, void* d_ws, size_t ws_size,
                              hipStream_t stream) {
    const float* x     = (const float*)d_in[0];
    const int*   edge  = (const int*)d_in[1];   // [2][E]
    const int*   users = (const int*)d_in[2];
    const int*   movies= (const int*)d_in[3];
    const float* W1    = (const float*)d_in[4];
    const float* b1    = (const float*)d_in[5];
    const float* W2    = (const float*)d_in[6];
    const float* b2    = (const float*)d_in[7];
    const float* fc_w  = (const float*)d_in[8];
    const float* fc_b  = (const float*)d_in[9];
    float* out = (float*)d_out;

    const int IN_DIM = 128;
    const int n       = in_sizes[0] / IN_DIM;  // 100000
    const int n_edges = in_sizes[1] / 2;       // 1200000 (divisible by 4)
    const int batch   = in_sizes[2];           // 8192

    const int* esrc = edge;
    const int* edst = edge + n_edges;

    char* ws = (char*)d_ws;
    size_t o = 0;
    auto alloc = [&](size_t bytes) { void* p = ws + o; o = (o + bytes + 255) & ~(size_t)255; return p; };
    int*   deg     = (int*)  alloc(sizeof(int) * n);
    int*   tmp     = (int*)  alloc(sizeof(int) * n);
    int*   bsum    = (int*)  alloc(sizeof(int) * 128);
    int*   boff    = (int*)  alloc(sizeof(int) * 129);
    int*   row_ptr = (int*)  alloc(sizeof(int) * (n + 1));
    int*   rel     = (int*)  alloc(sizeof(int) * n_edges);
    int*   col     = (int*)  alloc(sizeof(int) * n_edges);
    float* dinv    = (float*)alloc(sizeof(float) * n);
    float* B       = (float*)alloc(sizeof(float) * (size_t)n * HID);
    float* C       = (float*)alloc(sizeof(float) * (size_t)n * HID);

    const int nb1024 = (n + 1023) / 1024;      // 98 (<=128)
    const int n4     = n_edges / 4;            // 300000 int4s
    const int vb     = (n4 + 255) / 256;       // 1172 blocks

    // ---- CSR build + norm ----
    zero_int_kernel<<<(n + 255) / 256, 256, 0, stream>>>(deg, n);
    count_rel_kernel<<<vb, 256, 0, stream>>>((const int4*)edst, deg, (int4*)rel, n4);
    scan_partial_kernel<<<nb1024, 1024, 0, stream>>>(deg, tmp, bsum, n);
    scan_sums_kernel<<<1, 128, 0, stream>>>(bsum, boff, nb1024);
    finalize_rowptr_kernel<<<(n + 256) / 256, 256, 0, stream>>>(tmp, boff, deg, row_ptr, dinv, n);
    fill2_kernel<<<vb, 256, 0, stream>>>((const int4*)esrc, (const int4*)edst, row_ptr,
                                         (const int4*)rel, col, n4);

    // ---- layer 1 ----
    gemm_tile_kernel<128><<<(n + 63) / 64, 256, 0, stream>>>(x, W1, dinv, B, n);   // B = hs1
    gather_kernel<<<2048, 256, 0, stream>>>(B, row_ptr, col, dinv, b1, C, n);      // C = h1

    // ---- layer 2 ----
    gemm_tile_kernel<64><<<(n + 63) / 64, 256, 0, stream>>>(C, W2, dinv, B, n);    // B = hs2
    gather_kernel<<<2048, 256, 0, stream>>>(B, row_ptr, col, dinv, b2, C, n);      // C = h2

    // ---- prediction head ----
    final_kernel<<<2048, 256, 0, stream>>>(C, users, movies, fc_w, fc_b, out, batch);
}